// Round 5
// baseline (223.197 us; speedup 1.0000x reference)
//
#include <hip/hip_runtime.h>
#include <math.h>

#define NQ      14
#define NSTATE  16384
#define BATCH   128
#define DEPTH   3
#define NOBS    11
#define KDIM    16
#define NOFF    120
#define INDIM   784
#define OUTDIM  10

// skew on complex index: logical a -> physical a + (a>>4) (float2 units)
__device__ __forceinline__ int F2(int a) { return a + (a >> 4); }
#define PHYS2 (NSTATE + (NSTATE >> 4))   // 17408 float2 = 136 KB

// force block-uniform value into SGPR
__device__ __forceinline__ float sbc(float x) {
  return __int_as_float(__builtin_amdgcn_readfirstlane(__float_as_int(x)));
}

// ---------------------------------------------------------------------------
// Kernel 1: encoding GEMM. One wave per (g,b) pair -> theta[g*128+b][15].
// ---------------------------------------------------------------------------
__global__ __launch_bounds__(256) void enc_kernel(
    const float* __restrict__ x, const float* __restrict__ W,
    const float* __restrict__ bvec, float* __restrict__ theta)
{
  int wave = ((blockIdx.x << 2) | (threadIdx.x >> 6));   // 0..3327
  int lane = threadIdx.x & 63;
  int g = wave >> 7;
  int b = wave & 127;

  const float4* x4 = (const float4*)(x + (size_t)b * INDIM);        // 196 f4
  const float4* w4 = (const float4*)(W + (size_t)g * 15 * INDIM);

  float acc[15];
#pragma unroll
  for (int m = 0; m < 15; ++m) acc[m] = 0.f;
#pragma unroll
  for (int it = 0; it < 4; ++it) {
    int j4 = lane + it * 64;
    if (j4 < 196) {
      float4 xv = x4[j4];
#pragma unroll
      for (int m = 0; m < 15; ++m) {
        float4 wv = w4[m * 196 + j4];
        acc[m] = fmaf(xv.x, wv.x, fmaf(xv.y, wv.y, fmaf(xv.z, wv.z, fmaf(xv.w, wv.w, acc[m]))));
      }
    }
  }
#pragma unroll
  for (int m = 0; m < 15; ++m) {
#pragma unroll
    for (int off = 32; off; off >>= 1) acc[m] += __shfl_xor(acc[m], off);
  }
  if (lane == 0) {
#pragma unroll
    for (int m = 0; m < 15; ++m) theta[(size_t)wave * 15 + m] = acc[m] + bvec[g * 15 + m];
  }
}

// ---------------------------------------------------------------------------
// Kernel 2: U = expm(i * sum th_m P_m). FOUR lanes per matrix; lane j owns
// column j of T. G replicated per lane; squarings via intra-group shuffles.
// ---------------------------------------------------------------------------
__global__ __launch_bounds__(256) void expm_kernel(
    const float* __restrict__ theta, float2* __restrict__ Ubuf)
{
  int gid  = blockIdx.x * 256 + threadIdx.x;   // 0..13311
  int pair = gid >> 2;                         // 0..3327
  int j    = gid & 3;                          // column
  int lane = threadIdx.x & 63;
  int grp  = lane & 60;

  const float* th = theta + (size_t)pair * 15;

  const float pr_[4][4] = {{1,0,0,1},{0,1,1,0},{0,0,0,0},{1,0,0,-1}};
  const float pi_[4][4] = {{0,0,0,0},{0,0,0,0},{0,-1,1,0},{0,0,0,0}};

  float Hre[16], Him[16];
#pragma unroll
  for (int e = 0; e < 16; ++e) { Hre[e] = 0.f; Him[e] = 0.f; }
  float tsum = 0.f;
#pragma unroll
  for (int m = 0; m < 15; ++m) {
    float tv = th[m];
    tsum += fabsf(tv);
    const int code = m + 1;
    const int a = code >> 2, c = code & 3;
#pragma unroll
    for (int i = 0; i < 4; ++i)
#pragma unroll
      for (int jj = 0; jj < 4; ++jj) {
        float ar = pr_[a][(i >> 1) * 2 + (jj >> 1)], ai = pi_[a][(i >> 1) * 2 + (jj >> 1)];
        float br = pr_[c][(i & 1) * 2 + (jj & 1)],   bi = pi_[c][(i & 1) * 2 + (jj & 1)];
        Hre[i * 4 + jj] += tv * (ar * br - ai * bi);
        Him[i * 4 + jj] += tv * (ar * bi + ai * br);
      }
  }
  int s = 0;
  if (tsum > 0.25f) {
    s = (int)ceilf(log2f(tsum * 4.0f));
    if (s < 0) s = 0;
    if (s > 14) s = 14;
  }
  float sc = exp2f((float)(-s));
  float Gre[16], Gim[16];
#pragma unroll
  for (int e = 0; e < 16; ++e) { Gre[e] = -Him[e] * sc; Gim[e] = Hre[e] * sc; }

  float Tcr[4], Tci[4];
#pragma unroll
  for (int i = 0; i < 4; ++i) {
    Tcr[i] = Gre[i * 4 + j] * (1.f / 9.f) + ((i == j) ? 1.f : 0.f);
    Tci[i] = Gim[i * 4 + j] * (1.f / 9.f);
  }
#pragma unroll
  for (int k = 8; k >= 1; --k) {
    float nr[4], ni[4];
    float invk = 1.0f / (float)k;
#pragma unroll
    for (int i = 0; i < 4; ++i) {
      float xr = 0.f, xi = 0.f;
#pragma unroll
      for (int l = 0; l < 4; ++l) {
        xr = fmaf(Gre[i * 4 + l], Tcr[l], fmaf(-Gim[i * 4 + l], Tci[l], xr));
        xi = fmaf(Gre[i * 4 + l], Tci[l], fmaf( Gim[i * 4 + l], Tcr[l], xi));
      }
      nr[i] = invk * xr + ((i == j) ? 1.f : 0.f);
      ni[i] = invk * xi;
    }
#pragma unroll
    for (int i = 0; i < 4; ++i) { Tcr[i] = nr[i]; Tci[i] = ni[i]; }
  }
  for (int it = 0; it < s; ++it) {
    float nr[4] = {0.f, 0.f, 0.f, 0.f}, ni[4] = {0.f, 0.f, 0.f, 0.f};
#pragma unroll
    for (int l = 0; l < 4; ++l) {
      int src = grp | l;
      float tlr = Tcr[l], tli = Tci[l];
#pragma unroll
      for (int i = 0; i < 4; ++i) {
        float br = __shfl(Tcr[i], src);
        float bi = __shfl(Tci[i], src);
        nr[i] = fmaf(br, tlr, fmaf(-bi, tli, nr[i]));
        ni[i] = fmaf(br, tli, fmaf( bi, tlr, ni[i]));
      }
    }
#pragma unroll
    for (int i = 0; i < 4; ++i) { Tcr[i] = nr[i]; Tci[i] = ni[i]; }
  }
#pragma unroll
  for (int i = 0; i < 4; ++i)
    Ubuf[(size_t)pair * 16 + i * 4 + j] = make_float2(Tcr[i], Tci[i]);
}

// ---------------------------------------------------------------------------
// qsim helpers
// ---------------------------------------------------------------------------
template<int S>
__device__ __forceinline__ int grpbase(int t) {
  return ((t >> S) << (S + 4)) | (t & ((1 << S) - 1));
}
template<int S>
__device__ __forceinline__ void ldgrp(const float2* st, int base, float* vr, float* vi) {
#pragma unroll
  for (int k = 0; k < 16; ++k) {
    float2 v = st[F2(base + (k << S))];
    vr[k] = v.x; vi[k] = v.y;
  }
}
template<int S>
__device__ __forceinline__ void stgrp(float2* st, int base, const float* vr, const float* vi) {
#pragma unroll
  for (int k = 0; k < 16; ++k) st[F2(base + (k << S))] = make_float2(vr[k], vi[k]);
}
__device__ __forceinline__ int base2s(int t) {
  return ((t >> 7) << 11) | (((t >> 5) & 3) << 7) | (t & 31);
}
__device__ __forceinline__ int addr2s(int base, int k) {
  return base + ((k >> 2) << 9) + ((k & 3) << 5);
}
__device__ __forceinline__ void ldgrp2(const float2* st, int base, float* vr, float* vi) {
#pragma unroll
  for (int k = 0; k < 16; ++k) {
    float2 v = st[F2(addr2s(base, k))];
    vr[k] = v.x; vi[k] = v.y;
  }
}
__device__ __forceinline__ void stgrp2(float2* st, int base, const float* vr, const float* vi) {
#pragma unroll
  for (int k = 0; k < 16; ++k) st[F2(addr2s(base, k))] = make_float2(vr[k], vi[k]);
}

__device__ __forceinline__ void loadU(const float2* __restrict__ Ug, float* ur, float* ui) {
#pragma unroll
  for (int e = 0; e < 16; ++e) {
    float2 u = Ug[e];
    ur[e] = sbc(u.x); ui[e] = sbc(u.y);
  }
}

__device__ __forceinline__ void applyU_hi(float* vr, float* vi, const float* ur, const float* ui) {
#pragma unroll
  for (int j2 = 0; j2 < 4; ++j2) {
    float ar[4], ai[4];
#pragma unroll
    for (int j = 0; j < 4; ++j) { ar[j] = vr[4 * j + j2]; ai[j] = vi[4 * j + j2]; }
#pragma unroll
    for (int i = 0; i < 4; ++i) {
      float xr = 0.f, xi = 0.f;
#pragma unroll
      for (int j = 0; j < 4; ++j) {
        xr = fmaf(ur[4 * i + j], ar[j], fmaf(-ui[4 * i + j], ai[j], xr));
        xi = fmaf(ur[4 * i + j], ai[j], fmaf( ui[4 * i + j], ar[j], xi));
      }
      vr[4 * i + j2] = xr; vi[4 * i + j2] = xi;
    }
  }
}
__device__ __forceinline__ void applyU_lo(float* vr, float* vi, const float* ur, const float* ui) {
#pragma unroll
  for (int i2 = 0; i2 < 4; ++i2) {
    float ar[4], ai[4];
#pragma unroll
    for (int j = 0; j < 4; ++j) { ar[j] = vr[4 * i2 + j]; ai[j] = vi[4 * i2 + j]; }
#pragma unroll
    for (int i = 0; i < 4; ++i) {
      float xr = 0.f, xi = 0.f;
#pragma unroll
      for (int j = 0; j < 4; ++j) {
        xr = fmaf(ur[4 * i + j], ar[j], fmaf(-ui[4 * i + j], ai[j], xr));
        xi = fmaf(ur[4 * i + j], ai[j], fmaf( ui[4 * i + j], ar[j], xi));
      }
      vr[4 * i2 + i] = xr; vi[4 * i2 + i] = xi;
    }
  }
}
__device__ __forceinline__ void applyU_mid(float* vr, float* vi, const float* ur, const float* ui) {
#pragma unroll
  for (int o = 0; o < 4; ++o) {
    const int kb = ((o >> 1) << 3) | (o & 1);
    float ar[4], ai[4];
#pragma unroll
    for (int j = 0; j < 4; ++j) { ar[j] = vr[kb | (j << 1)]; ai[j] = vi[kb | (j << 1)]; }
#pragma unroll
    for (int i = 0; i < 4; ++i) {
      float xr = 0.f, xi = 0.f;
#pragma unroll
      for (int j = 0; j < 4; ++j) {
        xr = fmaf(ur[4 * i + j], ar[j], fmaf(-ui[4 * i + j], ai[j], xr));
        xi = fmaf(ur[4 * i + j], ai[j], fmaf( ui[4 * i + j], ar[j], xi));
      }
      vr[kb | (i << 1)] = xr; vi[kb | (i << 1)] = xi;
    }
  }
}

template<int B>
__device__ __forceinline__ void ry16(float* vr, float* vi, float c, float s) {
#pragma unroll
  for (int k = 0; k < 16; ++k) {
    if (!(k & (1 << B))) {
      const int k1 = k | (1 << B);
      float r0 = vr[k], i0 = vi[k], r1 = vr[k1], i1 = vi[k1];
      vr[k]  = fmaf(c, r0, -s * r1);  vi[k]  = fmaf(c, i0, -s * i1);
      vr[k1] = fmaf(s, r0,  c * r1);  vi[k1] = fmaf(s, i0,  c * i1);
    }
  }
}
template<int CB, int TB>
__device__ __forceinline__ void cx16(float* vr, float* vi) {
#pragma unroll
  for (int k = 0; k < 16; ++k) {
    if ((k & (1 << CB)) && !(k & (1 << TB))) {
      const int k1 = k | (1 << TB);
      float tr = vr[k]; vr[k] = vr[k1]; vr[k1] = tr;
      float ti = vi[k]; vi[k] = vi[k1]; vi[k1] = ti;
    }
  }
}

template<int S>
__device__ __forceinline__ void enc_pass3(float2* st, const float2* __restrict__ U,
                                          int gHi, int gLo, int gMid, int b, int t) {
  float ur[16], ui[16], vr[16], vi[16];
  int base = grpbase<S>(t);
  ldgrp<S>(st, base, vr, vi);
  loadU(U + ((size_t)gHi  * BATCH + b) * 16, ur, ui); applyU_hi (vr, vi, ur, ui);
  loadU(U + ((size_t)gLo  * BATCH + b) * 16, ur, ui); applyU_lo (vr, vi, ur, ui);
  loadU(U + ((size_t)gMid * BATCH + b) * 16, ur, ui); applyU_mid(vr, vi, ur, ui);
  stgrp<S>(st, base, vr, vi);
}
__device__ __forceinline__ void enc_passD(float2* st, const float2* __restrict__ U,
                                          int gLo, int gMid, int b, int t) {
  float ur[16], ui[16], vr[16], vi[16];
  int base = t << 4;
  ldgrp<0>(st, base, vr, vi);
  loadU(U + ((size_t)gLo  * BATCH + b) * 16, ur, ui); applyU_lo (vr, vi, ur, ui);
  loadU(U + ((size_t)gMid * BATCH + b) * 16, ur, ui); applyU_mid(vr, vi, ur, ui);
  stgrp<0>(st, base, vr, vi);
}
__device__ __forceinline__ void enc_passE(float2* st, const float2* __restrict__ U,
                                          int gA, int gB, int b, int t) {
  float ur[16], ui[16], vr[16], vi[16];
  int base = base2s(t);
  ldgrp2(st, base, vr, vi);
  loadU(U + ((size_t)gA * BATCH + b) * 16, ur, ui); applyU_hi(vr, vi, ur, ui);
  loadU(U + ((size_t)gB * BATCH + b) * 16, ur, ui); applyU_lo(vr, vi, ur, ui);
  stgrp2(st, base, vr, vi);
}
template<int S>
__device__ __forceinline__ void var_pass3(float2* st, const float* __restrict__ vp,
                                          int l, int qbase, int t) {
  float vr[16], vi[16];
  int base = grpbase<S>(t);
  ldgrp<S>(st, base, vr, vi);
  float c[4], sn[4];
#pragma unroll
  for (int i = 0; i < 4; ++i) {
    float a = sbc(vp[l * NQ + qbase + i]) * 0.5f;
    c[i] = cosf(a); sn[i] = sinf(a);
  }
  ry16<3>(vr, vi, c[0], sn[0]);
  ry16<2>(vr, vi, c[1], sn[1]);
  ry16<1>(vr, vi, c[2], sn[2]);
  ry16<0>(vr, vi, c[3], sn[3]);
  cx16<3, 2>(vr, vi);
  cx16<1, 0>(vr, vi);
  cx16<2, 1>(vr, vi);
  stgrp<S>(st, base, vr, vi);
}
__device__ __forceinline__ void var_passD(float2* st, const float* __restrict__ vp,
                                          int l, int t) {
  float vr[16], vi[16];
  int base = t << 4;
  ldgrp<0>(st, base, vr, vi);
  float a0 = sbc(vp[l * NQ + 12]) * 0.5f;
  float a1 = sbc(vp[l * NQ + 13]) * 0.5f;
  ry16<1>(vr, vi, cosf(a0), sinf(a0));
  ry16<0>(vr, vi, cosf(a1), sinf(a1));
  cx16<1, 0>(vr, vi);
  cx16<2, 1>(vr, vi);
  stgrp<0>(st, base, vr, vi);
}
__device__ __forceinline__ void var_passE(float2* st, int t) {
  float vr[16], vi[16];
  int base = base2s(t);
  ldgrp2(st, base, vr, vi);
  cx16<3, 2>(vr, vi);
  cx16<1, 0>(vr, vi);
  stgrp2(st, base, vr, vi);
}

// ---------------------------------------------------------------------------
// Kernel 3: gate evolution only. One block per batch element; final state to
// global memory (unskewed, coalesced).
// ---------------------------------------------------------------------------
__global__ __launch_bounds__(1024) void qsim_gates(
    const float2* __restrict__ U, const float* __restrict__ var_params,
    float2* __restrict__ gstate)
{
  __shared__ float2 st[PHYS2];

  const int t = threadIdx.x;
  const int b = blockIdx.x;

  for (int i = t; i < PHYS2; i += 1024)
    st[i] = (i == 0) ? make_float2(1.f, 0.f) : make_float2(0.f, 0.f);
  __syncthreads();

  for (int nb = 0; nb < 2; ++nb) {
    int gI = nb * 13;
    enc_pass3<10>(st, U, gI + 0, gI + 1, gI + 7,  b, t); __syncthreads();
    enc_pass3<6 >(st, U, gI + 2, gI + 3, gI + 9,  b, t); __syncthreads();
    enc_pass3<2 >(st, U, gI + 4, gI + 5, gI + 11, b, t); __syncthreads();
    enc_passD    (st, U, gI + 6, gI + 12,         b, t); __syncthreads();
    enc_passE    (st, U, gI + 8, gI + 10,         b, t); __syncthreads();
  }

  for (int l = 0; l < DEPTH; ++l) {
    var_pass3<10>(st, var_params, l, 0, t); __syncthreads();
    var_pass3<6 >(st, var_params, l, 4, t); __syncthreads();
    var_pass3<2 >(st, var_params, l, 8, t); __syncthreads();
    var_passD    (st, var_params, l,    t); __syncthreads();
    var_passE    (st, t);                   __syncthreads();
  }

  float2* gout = gstate + ((size_t)b << 14);
#pragma unroll
  for (int j = 0; j < 16; ++j) {
    int i = t + (j << 10);
    gout[i] = st[F2(i)];
  }
}

// ---------------------------------------------------------------------------
// Kernel 4: expectation values + head. One block per (w,b); block index
// w*128+b so XCD = b%8 is constant across the 11 w-sweeps (state stays in
// its XCD's L2). 256 threads x 4 groups of 16 amps.
// ---------------------------------------------------------------------------
__global__ __launch_bounds__(256) void obs_kernel(
    const float2* __restrict__ gstate,
    const float* __restrict__ A, const float* __restrict__ Bp,
    const float* __restrict__ D, const float* __restrict__ Wh,
    const float* __restrict__ bh, float* __restrict__ out)
{
  __shared__ float ob[256];
  __shared__ float red[4];

  const int t = threadIdx.x;
  const int w = blockIdx.x >> 7;
  const int b = blockIdx.x & 127;

  // stage A/B/D for this observable
  {
    float v;
    if (t < NOFF)                 v = A[w * NOFF + t];
    else if (t < 2 * NOFF)        v = Bp[w * NOFF + (t - NOFF)];
    else                          v = D[w * KDIM + (t - 2 * NOFF)];
    ob[t] = v;
  }
  __syncthreads();

  const float2* stb = gstate + ((size_t)b << 14);
  const int shift = 10 - w;
  const int mask = (1 << shift) - 1;

  float E = 0.f;
#pragma unroll
  for (int it = 0; it < 4; ++it) {
    int gg = (it << 8) | t;
    int hi = gg >> shift;
    int lo = gg & mask;
    int base = (hi << (shift + 4)) | lo;
    float sr[16], si[16];
#pragma unroll
    for (int k = 0; k < 16; ++k) {
      float2 v = stb[base + (k << shift)];
      sr[k] = v.x; si[k] = v.y;
    }
#pragma unroll
    for (int k = 0; k < 15; ++k)
      E = fmaf(ob[240 + k + 1], sr[k] * sr[k] + si[k] * si[k], E);
#pragma unroll
    for (int k = 1; k < 16; ++k) {
#pragma unroll
      for (int l2 = 0; l2 < k; ++l2) {
        const int pidx = (k * (k - 1)) / 2 + l2;
        float t1 = sr[k] * sr[l2] + si[k] * si[l2];
        float t2 = si[k] * sr[l2] - sr[k] * si[l2];
        E = fmaf(ob[pidx], t1, fmaf(ob[NOFF + pidx], t2, E));
      }
    }
  }
#pragma unroll
  for (int off = 32; off; off >>= 1) E += __shfl_xor(E, off);
  if ((t & 63) == 0) red[t >> 6] = E;
  __syncthreads();

  if (t < OUTDIM) {
    float q = 2.0f * (red[0] + red[1] + red[2] + red[3]);
    float o = fmaf(Wh[t * NOBS + w], q, (w == 0) ? bh[t] : 0.f);
    atomicAdd(&out[b * OUTDIM + t], o);
  }
}

extern "C" void kernel_launch(void* const* d_in, const int* in_sizes, int n_in,
                              void* d_out, int out_size, void* d_ws, size_t ws_size,
                              hipStream_t stream) {
  const float* x          = (const float*)d_in[0];
  const float* W_enc      = (const float*)d_in[1];
  const float* b_enc      = (const float*)d_in[2];
  const float* var_params = (const float*)d_in[3];
  const float* A          = (const float*)d_in[4];
  const float* Bp         = (const float*)d_in[5];
  const float* D          = (const float*)d_in[6];
  const float* W_head     = (const float*)d_in[7];
  const float* b_head     = (const float*)d_in[8];
  float* out = (float*)d_out;

  char* wsb = (char*)d_ws;
  float*  theta  = (float*)wsb;                          // 3328*15 f32 = 199680 B
  float2* Ubuf   = (float2*)(wsb + 199680);              // 3328*16 f2  = 425984 B
  float2* gstate = (float2*)(wsb + 199680 + 425984);     // 128*16384 f2 = 16 MB

  hipMemsetAsync(out, 0, (size_t)out_size * sizeof(float), stream);
  enc_kernel <<<832, 256, 0, stream>>>(x, W_enc, b_enc, theta);
  expm_kernel<<<52,  256, 0, stream>>>(theta, Ubuf);
  qsim_gates <<<128, 1024, 0, stream>>>(Ubuf, var_params, gstate);
  obs_kernel <<<NOBS * BATCH, 256, 0, stream>>>(gstate, A, Bp, D,
                                                W_head, b_head, out);
}

// Round 6
// 187.981 us; speedup vs baseline: 1.1873x; 1.1873x over previous
//
#include <hip/hip_runtime.h>
#include <math.h>

#define NQ      14
#define NSTATE  16384
#define BATCH   128
#define DEPTH   3
#define NOBS    11
#define KDIM    16
#define NOFF    120
#define INDIM   784
#define OUTDIM  10

// skew on complex index: logical a -> physical a + (a>>4) (float2 units)
__device__ __forceinline__ int F2(int a) { return a + (a >> 4); }
#define PHYS2 (NSTATE + (NSTATE >> 4))   // 17408 float2 = 136 KB

// force block-uniform value into SGPR
__device__ __forceinline__ float sbc(float x) {
  return __int_as_float(__builtin_amdgcn_readfirstlane(__float_as_int(x)));
}

// ---------------------------------------------------------------------------
// Kernel 1: encoding GEMM + expm fused. One wave per (g,b); after the
// butterfly reduce ALL lanes hold theta, lanes 0-3 compute the 4 columns of
// U = expm(i*sum th_m P_m) (scaling-and-squaring, squarings via shuffles).
// ---------------------------------------------------------------------------
__global__ __launch_bounds__(256) void enc_expm_kernel(
    const float* __restrict__ x, const float* __restrict__ W,
    const float* __restrict__ bvec, float2* __restrict__ Ubuf)
{
  int wave = ((blockIdx.x << 2) | (threadIdx.x >> 6));   // 0..3327 = g*128+b
  int lane = threadIdx.x & 63;
  int g = wave >> 7;
  int b = wave & 127;

  const float4* x4 = (const float4*)(x + (size_t)b * INDIM);        // 196 f4
  const float4* w4 = (const float4*)(W + (size_t)g * 15 * INDIM);

  float acc[15];
#pragma unroll
  for (int m = 0; m < 15; ++m) acc[m] = 0.f;
#pragma unroll
  for (int it = 0; it < 4; ++it) {
    int j4 = lane + it * 64;
    if (j4 < 196) {
      float4 xv = x4[j4];
#pragma unroll
      for (int m = 0; m < 15; ++m) {
        float4 wv = w4[m * 196 + j4];
        acc[m] = fmaf(xv.x, wv.x, fmaf(xv.y, wv.y, fmaf(xv.z, wv.z, fmaf(xv.w, wv.w, acc[m]))));
      }
    }
  }
#pragma unroll
  for (int m = 0; m < 15; ++m) {
#pragma unroll
    for (int off = 32; off; off >>= 1) acc[m] += __shfl_xor(acc[m], off);
  }

  if (lane < 4) {
    const int j = lane;                 // column owned by this lane
    float th[15];
#pragma unroll
    for (int m = 0; m < 15; ++m) th[m] = acc[m] + bvec[g * 15 + m];

    const float pr_[4][4] = {{1,0,0,1},{0,1,1,0},{0,0,0,0},{1,0,0,-1}};
    const float pi_[4][4] = {{0,0,0,0},{0,0,0,0},{0,-1,1,0},{0,0,0,0}};
    float Hre[16], Him[16];
#pragma unroll
    for (int e = 0; e < 16; ++e) { Hre[e] = 0.f; Him[e] = 0.f; }
    float tsum = 0.f;
#pragma unroll
    for (int m = 0; m < 15; ++m) {
      float tv = th[m];
      tsum += fabsf(tv);
      const int code = m + 1;
      const int a = code >> 2, c = code & 3;
#pragma unroll
      for (int i = 0; i < 4; ++i)
#pragma unroll
        for (int jj = 0; jj < 4; ++jj) {
          float ar = pr_[a][(i >> 1) * 2 + (jj >> 1)], ai = pi_[a][(i >> 1) * 2 + (jj >> 1)];
          float br = pr_[c][(i & 1) * 2 + (jj & 1)],   bi = pi_[c][(i & 1) * 2 + (jj & 1)];
          Hre[i * 4 + jj] += tv * (ar * br - ai * bi);
          Him[i * 4 + jj] += tv * (ar * bi + ai * br);
        }
    }
    int s = 0;
    if (tsum > 0.25f) {
      s = (int)ceilf(log2f(tsum * 4.0f));
      if (s < 0) s = 0;
      if (s > 14) s = 14;
    }
    float sc = exp2f((float)(-s));
    float Gre[16], Gim[16];
#pragma unroll
    for (int e = 0; e < 16; ++e) { Gre[e] = -Him[e] * sc; Gim[e] = Hre[e] * sc; }

    float Tcr[4], Tci[4];
#pragma unroll
    for (int i = 0; i < 4; ++i) {
      Tcr[i] = Gre[i * 4 + j] * (1.f / 9.f) + ((i == j) ? 1.f : 0.f);
      Tci[i] = Gim[i * 4 + j] * (1.f / 9.f);
    }
#pragma unroll
    for (int k = 8; k >= 1; --k) {
      float nr[4], ni[4];
      float invk = 1.0f / (float)k;
#pragma unroll
      for (int i = 0; i < 4; ++i) {
        float xr = 0.f, xi = 0.f;
#pragma unroll
        for (int l = 0; l < 4; ++l) {
          xr = fmaf(Gre[i * 4 + l], Tcr[l], fmaf(-Gim[i * 4 + l], Tci[l], xr));
          xi = fmaf(Gre[i * 4 + l], Tci[l], fmaf( Gim[i * 4 + l], Tcr[l], xi));
        }
        nr[i] = invk * xr + ((i == j) ? 1.f : 0.f);
        ni[i] = invk * xi;
      }
#pragma unroll
      for (int i = 0; i < 4; ++i) { Tcr[i] = nr[i]; Tci[i] = ni[i]; }
    }
    for (int it = 0; it < s; ++it) {
      float nr[4] = {0.f, 0.f, 0.f, 0.f}, ni[4] = {0.f, 0.f, 0.f, 0.f};
#pragma unroll
      for (int l = 0; l < 4; ++l) {
        float tlr = Tcr[l], tli = Tci[l];   // T[l,j] local (pre-update)
#pragma unroll
        for (int i = 0; i < 4; ++i) {
          float br = __shfl(Tcr[i], l);     // T[i,l] from lane l
          float bi = __shfl(Tci[i], l);
          nr[i] = fmaf(br, tlr, fmaf(-bi, tli, nr[i]));
          ni[i] = fmaf(br, tli, fmaf( bi, tlr, ni[i]));
        }
      }
#pragma unroll
      for (int i = 0; i < 4; ++i) { Tcr[i] = nr[i]; Tci[i] = ni[i]; }
    }
#pragma unroll
    for (int i = 0; i < 4; ++i)
      Ubuf[(size_t)wave * 16 + i * 4 + j] = make_float2(Tcr[i], Tci[i]);
  }
}

// ---------------------------------------------------------------------------
// qsim helpers
// ---------------------------------------------------------------------------
template<int S>
__device__ __forceinline__ int grpbase(int t) {
  return ((t >> S) << (S + 4)) | (t & ((1 << S) - 1));
}
template<int S>
__device__ __forceinline__ void ldgrp(const float2* st, int base, float* vr, float* vi) {
#pragma unroll
  for (int k = 0; k < 16; ++k) {
    float2 v = st[F2(base + (k << S))];
    vr[k] = v.x; vi[k] = v.y;
  }
}
template<int S>
__device__ __forceinline__ void stgrp(float2* st, int base, const float* vr, const float* vi) {
#pragma unroll
  for (int k = 0; k < 16; ++k) st[F2(base + (k << S))] = make_float2(vr[k], vi[k]);
}
__device__ __forceinline__ int base2s(int t) {
  return ((t >> 7) << 11) | (((t >> 5) & 3) << 7) | (t & 31);
}
__device__ __forceinline__ int addr2s(int base, int k) {
  return base + ((k >> 2) << 9) + ((k & 3) << 5);
}
__device__ __forceinline__ void ldgrp2(const float2* st, int base, float* vr, float* vi) {
#pragma unroll
  for (int k = 0; k < 16; ++k) {
    float2 v = st[F2(addr2s(base, k))];
    vr[k] = v.x; vi[k] = v.y;
  }
}
__device__ __forceinline__ void stgrp2(float2* st, int base, const float* vr, const float* vi) {
#pragma unroll
  for (int k = 0; k < 16; ++k) st[F2(addr2s(base, k))] = make_float2(vr[k], vi[k]);
}

__device__ __forceinline__ void loadU(const float2* __restrict__ Ug, float* ur, float* ui) {
#pragma unroll
  for (int e = 0; e < 16; ++e) {
    float2 u = Ug[e];
    ur[e] = sbc(u.x); ui[e] = sbc(u.y);
  }
}

__device__ __forceinline__ void applyU_hi(float* vr, float* vi, const float* ur, const float* ui) {
#pragma unroll
  for (int j2 = 0; j2 < 4; ++j2) {
    float ar[4], ai[4];
#pragma unroll
    for (int j = 0; j < 4; ++j) { ar[j] = vr[4 * j + j2]; ai[j] = vi[4 * j + j2]; }
#pragma unroll
    for (int i = 0; i < 4; ++i) {
      float xr = 0.f, xi = 0.f;
#pragma unroll
      for (int j = 0; j < 4; ++j) {
        xr = fmaf(ur[4 * i + j], ar[j], fmaf(-ui[4 * i + j], ai[j], xr));
        xi = fmaf(ur[4 * i + j], ai[j], fmaf( ui[4 * i + j], ar[j], xi));
      }
      vr[4 * i + j2] = xr; vi[4 * i + j2] = xi;
    }
  }
}
__device__ __forceinline__ void applyU_lo(float* vr, float* vi, const float* ur, const float* ui) {
#pragma unroll
  for (int i2 = 0; i2 < 4; ++i2) {
    float ar[4], ai[4];
#pragma unroll
    for (int j = 0; j < 4; ++j) { ar[j] = vr[4 * i2 + j]; ai[j] = vi[4 * i2 + j]; }
#pragma unroll
    for (int i = 0; i < 4; ++i) {
      float xr = 0.f, xi = 0.f;
#pragma unroll
      for (int j = 0; j < 4; ++j) {
        xr = fmaf(ur[4 * i + j], ar[j], fmaf(-ui[4 * i + j], ai[j], xr));
        xi = fmaf(ur[4 * i + j], ai[j], fmaf( ui[4 * i + j], ar[j], xi));
      }
      vr[4 * i2 + i] = xr; vi[4 * i2 + i] = xi;
    }
  }
}
__device__ __forceinline__ void applyU_mid(float* vr, float* vi, const float* ur, const float* ui) {
#pragma unroll
  for (int o = 0; o < 4; ++o) {
    const int kb = ((o >> 1) << 3) | (o & 1);
    float ar[4], ai[4];
#pragma unroll
    for (int j = 0; j < 4; ++j) { ar[j] = vr[kb | (j << 1)]; ai[j] = vi[kb | (j << 1)]; }
#pragma unroll
    for (int i = 0; i < 4; ++i) {
      float xr = 0.f, xi = 0.f;
#pragma unroll
      for (int j = 0; j < 4; ++j) {
        xr = fmaf(ur[4 * i + j], ar[j], fmaf(-ui[4 * i + j], ai[j], xr));
        xi = fmaf(ur[4 * i + j], ai[j], fmaf( ui[4 * i + j], ar[j], xi));
      }
      vr[kb | (i << 1)] = xr; vi[kb | (i << 1)] = xi;
    }
  }
}

template<int B>
__device__ __forceinline__ void ry16(float* vr, float* vi, float c, float s) {
#pragma unroll
  for (int k = 0; k < 16; ++k) {
    if (!(k & (1 << B))) {
      const int k1 = k | (1 << B);
      float r0 = vr[k], i0 = vi[k], r1 = vr[k1], i1 = vi[k1];
      vr[k]  = fmaf(c, r0, -s * r1);  vi[k]  = fmaf(c, i0, -s * i1);
      vr[k1] = fmaf(s, r0,  c * r1);  vi[k1] = fmaf(s, i0,  c * i1);
    }
  }
}
template<int CB, int TB>
__device__ __forceinline__ void cx16(float* vr, float* vi) {
#pragma unroll
  for (int k = 0; k < 16; ++k) {
    if ((k & (1 << CB)) && !(k & (1 << TB))) {
      const int k1 = k | (1 << TB);
      float tr = vr[k]; vr[k] = vr[k1]; vr[k1] = tr;
      float ti = vi[k]; vi[k] = vi[k1]; vi[k1] = ti;
    }
  }
}

template<int S>
__device__ __forceinline__ void enc_pass3(float2* st, const float2* __restrict__ U,
                                          int gHi, int gLo, int gMid, int b, int t) {
  float ur[16], ui[16], vr[16], vi[16];
  int base = grpbase<S>(t);
  ldgrp<S>(st, base, vr, vi);
  loadU(U + ((size_t)gHi  * BATCH + b) * 16, ur, ui); applyU_hi (vr, vi, ur, ui);
  loadU(U + ((size_t)gLo  * BATCH + b) * 16, ur, ui); applyU_lo (vr, vi, ur, ui);
  loadU(U + ((size_t)gMid * BATCH + b) * 16, ur, ui); applyU_mid(vr, vi, ur, ui);
  stgrp<S>(st, base, vr, vi);
}
__device__ __forceinline__ void enc_passD(float2* st, const float2* __restrict__ U,
                                          int gLo, int gMid, int b, int t) {
  float ur[16], ui[16], vr[16], vi[16];
  int base = t << 4;
  ldgrp<0>(st, base, vr, vi);
  loadU(U + ((size_t)gLo  * BATCH + b) * 16, ur, ui); applyU_lo (vr, vi, ur, ui);
  loadU(U + ((size_t)gMid * BATCH + b) * 16, ur, ui); applyU_mid(vr, vi, ur, ui);
  stgrp<0>(st, base, vr, vi);
}
__device__ __forceinline__ void enc_passE(float2* st, const float2* __restrict__ U,
                                          int gA, int gB, int b, int t) {
  float ur[16], ui[16], vr[16], vi[16];
  int base = base2s(t);
  ldgrp2(st, base, vr, vi);
  loadU(U + ((size_t)gA * BATCH + b) * 16, ur, ui); applyU_hi(vr, vi, ur, ui);
  loadU(U + ((size_t)gB * BATCH + b) * 16, ur, ui); applyU_lo(vr, vi, ur, ui);
  stgrp2(st, base, vr, vi);
}
template<int S>
__device__ __forceinline__ void var_pass3(float2* st, const float* __restrict__ vp,
                                          int l, int qbase, int t) {
  float vr[16], vi[16];
  int base = grpbase<S>(t);
  ldgrp<S>(st, base, vr, vi);
  float c[4], sn[4];
#pragma unroll
  for (int i = 0; i < 4; ++i) {
    float a = sbc(vp[l * NQ + qbase + i]) * 0.5f;
    c[i] = cosf(a); sn[i] = sinf(a);
  }
  ry16<3>(vr, vi, c[0], sn[0]);
  ry16<2>(vr, vi, c[1], sn[1]);
  ry16<1>(vr, vi, c[2], sn[2]);
  ry16<0>(vr, vi, c[3], sn[3]);
  cx16<3, 2>(vr, vi);
  cx16<1, 0>(vr, vi);
  cx16<2, 1>(vr, vi);
  stgrp<S>(st, base, vr, vi);
}
__device__ __forceinline__ void var_passD(float2* st, const float* __restrict__ vp,
                                          int l, int t) {
  float vr[16], vi[16];
  int base = t << 4;
  ldgrp<0>(st, base, vr, vi);
  float a0 = sbc(vp[l * NQ + 12]) * 0.5f;
  float a1 = sbc(vp[l * NQ + 13]) * 0.5f;
  ry16<1>(vr, vi, cosf(a0), sinf(a0));
  ry16<0>(vr, vi, cosf(a1), sinf(a1));
  cx16<1, 0>(vr, vi);
  cx16<2, 1>(vr, vi);
  stgrp<0>(st, base, vr, vi);
}
__device__ __forceinline__ void var_passE(float2* st, int t) {
  float vr[16], vi[16];
  int base = base2s(t);
  ldgrp2(st, base, vr, vi);
  cx16<3, 2>(vr, vi);
  cx16<1, 0>(vr, vi);
  stgrp2(st, base, vr, vi);
}

// ---------------------------------------------------------------------------
// Kernel 2: statevector sim. TWO blocks per batch element (redundant gate
// evolution); obs split by w-parity. Observable coefficients are read
// directly from global with block-uniform indices -> scalar s_load path
// (keeps them off the LDS and vector-memory pipes).
// ---------------------------------------------------------------------------
__global__ __launch_bounds__(1024) void qsim_kernel(
    const float2* __restrict__ U, const float* __restrict__ var_params,
    const float* __restrict__ A, const float* __restrict__ Bp,
    const float* __restrict__ D, const float* __restrict__ Wh,
    const float* __restrict__ bh, float* __restrict__ out)
{
  __shared__ float2 st[PHYS2];
  __shared__ float red[6][16];       // per-(obs, wave) partials

  const int t = threadIdx.x;
  const int b = blockIdx.x >> 1;
  const int h = blockIdx.x & 1;      // obs parity this block handles
  const int nw = h ? 5 : 6;

  for (int i = t; i < PHYS2; i += 1024)
    st[i] = (i == 0) ? make_float2(1.f, 0.f) : make_float2(0.f, 0.f);
  __syncthreads();

  // ---- encoding: 2 blocks x 5 fused passes (13 gates each) ----
  for (int nb = 0; nb < 2; ++nb) {
    int gI = nb * 13;
    enc_pass3<10>(st, U, gI + 0, gI + 1, gI + 7,  b, t); __syncthreads();
    enc_pass3<6 >(st, U, gI + 2, gI + 3, gI + 9,  b, t); __syncthreads();
    enc_pass3<2 >(st, U, gI + 4, gI + 5, gI + 11, b, t); __syncthreads();
    enc_passD    (st, U, gI + 6, gI + 12,         b, t); __syncthreads();
    enc_passE    (st, U, gI + 8, gI + 10,         b, t); __syncthreads();
  }

  // ---- variational: 3 layers x 5 fused passes ----
  for (int l = 0; l < DEPTH; ++l) {
    var_pass3<10>(st, var_params, l, 0, t); __syncthreads();
    var_pass3<6 >(st, var_params, l, 4, t); __syncthreads();
    var_pass3<2 >(st, var_params, l, 8, t); __syncthreads();
    var_passD    (st, var_params, l,    t); __syncthreads();
    var_passE    (st, t);                   __syncthreads();
  }

  // ---- expectation values: y-form, coefficients via uniform global reads
  const int wave = t >> 6;
  for (int idx = 0; idx < nw; ++idx) {
    const int w = 2 * idx + h;                 // block-uniform
    const float* __restrict__ Aw = A + w * NOFF;
    const float* __restrict__ Bw = Bp + w * NOFF;
    const float* __restrict__ Dw = D + w * KDIM;
    const int shift = 10 - w;
    const int hi2 = t >> shift;
    const int lo = t & ((1 << shift) - 1);
    const int base2 = (hi2 << (shift + 4)) | lo;
    float sr[16], si[16];
#pragma unroll
    for (int k = 0; k < 16; ++k) {
      float2 v = st[F2(base2 + (k << shift))];
      sr[k] = v.x; si[k] = v.y;
    }
    // y_k = d_k s_k + sum_{l<k} (A_p + i B_p) s_l
    float yr[16], yi[16];
#pragma unroll
    for (int k = 0; k < 16; ++k) {
      float dk = (k < 15) ? Dw[k + 1] : 0.f;
      yr[k] = dk * sr[k];
      yi[k] = dk * si[k];
    }
#pragma unroll
    for (int k = 1; k < 16; ++k) {
#pragma unroll
      for (int l2 = 0; l2 < k; ++l2) {
        const int pidx = (k * (k - 1)) / 2 + l2;
        const float a = Aw[pidx];
        const float q = Bw[pidx];
        yr[k] = fmaf(a, sr[l2], fmaf(-q, si[l2], yr[k]));
        yi[k] = fmaf(a, si[l2], fmaf( q, sr[l2], yi[k]));
      }
    }
    float E = 0.f;
#pragma unroll
    for (int k = 0; k < 16; ++k)
      E = fmaf(sr[k], yr[k], fmaf(si[k], yi[k], E));
    E *= 2.0f;
#pragma unroll
    for (int off = 32; off; off >>= 1) E += __shfl_xor(E, off);
    if ((t & 63) == 0) red[idx][wave] = E;
  }
  __syncthreads();

  // ---- head: partial contribution, accumulated atomically ----
  if (t < OUTDIM) {
    float o = (h == 0) ? bh[t] : 0.f;
    for (int idx = 0; idx < nw; ++idx) {
      const int w = 2 * idx + h;
      float q = 0.f;
#pragma unroll
      for (int ww = 0; ww < 16; ++ww) q += red[idx][ww];
      o = fmaf(Wh[t * NOBS + w], q, o);
    }
    atomicAdd(&out[b * OUTDIM + t], o);
  }
}

extern "C" void kernel_launch(void* const* d_in, const int* in_sizes, int n_in,
                              void* d_out, int out_size, void* d_ws, size_t ws_size,
                              hipStream_t stream) {
  const float* x          = (const float*)d_in[0];
  const float* W_enc      = (const float*)d_in[1];
  const float* b_enc      = (const float*)d_in[2];
  const float* var_params = (const float*)d_in[3];
  const float* A          = (const float*)d_in[4];
  const float* Bp         = (const float*)d_in[5];
  const float* D          = (const float*)d_in[6];
  const float* W_head     = (const float*)d_in[7];
  const float* b_head     = (const float*)d_in[8];
  float* out = (float*)d_out;

  float2* Ubuf = (float2*)d_ws;   // 3328 * 16 float2 = 425984 B

  hipMemsetAsync(out, 0, (size_t)out_size * sizeof(float), stream);
  enc_expm_kernel<<<832, 256, 0, stream>>>(x, W_enc, b_enc, Ubuf);
  qsim_kernel<<<256, 1024, 0, stream>>>(Ubuf, var_params, A, Bp, D,
                                        W_head, b_head, out);
}

// Round 7
// 176.573 us; speedup vs baseline: 1.2641x; 1.0646x over previous
//
#include <hip/hip_runtime.h>
#include <math.h>

#define NQ      14
#define NSTATE  16384
#define BATCH   128
#define DEPTH   3
#define NOBS    11
#define KDIM    16
#define NOFF    120
#define INDIM   784
#define OUTDIM  10

// skew on complex index: logical a -> physical a + (a>>4) (float2 units)
__device__ __forceinline__ int F2(int a) { return a + (a >> 4); }
#define PHYS2 (NSTATE + (NSTATE >> 4))   // 17408 float2 = 136 KB

// force block-uniform value into SGPR
__device__ __forceinline__ float sbc(float x) {
  return __int_as_float(__builtin_amdgcn_readfirstlane(__float_as_int(x)));
}

// ---------------------------------------------------------------------------
// Kernel 1: encoding GEMM. One wave per (g,b) pair -> theta[g*128+b][15].
// ---------------------------------------------------------------------------
__global__ __launch_bounds__(256) void enc_kernel(
    const float* __restrict__ x, const float* __restrict__ W,
    const float* __restrict__ bvec, float* __restrict__ theta)
{
  int wave = ((blockIdx.x << 2) | (threadIdx.x >> 6));   // 0..3327
  int lane = threadIdx.x & 63;
  int g = wave >> 7;
  int b = wave & 127;

  const float4* x4 = (const float4*)(x + (size_t)b * INDIM);        // 196 f4
  const float4* w4 = (const float4*)(W + (size_t)g * 15 * INDIM);

  float acc[15];
#pragma unroll
  for (int m = 0; m < 15; ++m) acc[m] = 0.f;
#pragma unroll
  for (int it = 0; it < 4; ++it) {
    int j4 = lane + it * 64;
    if (j4 < 196) {
      float4 xv = x4[j4];
#pragma unroll
      for (int m = 0; m < 15; ++m) {
        float4 wv = w4[m * 196 + j4];
        acc[m] = fmaf(xv.x, wv.x, fmaf(xv.y, wv.y, fmaf(xv.z, wv.z, fmaf(xv.w, wv.w, acc[m]))));
      }
    }
  }
#pragma unroll
  for (int m = 0; m < 15; ++m) {
#pragma unroll
    for (int off = 32; off; off >>= 1) acc[m] += __shfl_xor(acc[m], off);
  }
  if (lane == 0) {
#pragma unroll
    for (int m = 0; m < 15; ++m) theta[(size_t)wave * 15 + m] = acc[m] + bvec[g * 15 + m];
  }
}

// ---------------------------------------------------------------------------
// Kernel 2: U = expm(i * sum th_m P_m). FOUR lanes per matrix; lane j owns
// column j of T. G replicated per lane; squarings via intra-group shuffles.
// ---------------------------------------------------------------------------
__global__ __launch_bounds__(256) void expm_kernel(
    const float* __restrict__ theta, float2* __restrict__ Ubuf)
{
  int gid  = blockIdx.x * 256 + threadIdx.x;   // 0..13311
  int pair = gid >> 2;                         // 0..3327
  int j    = gid & 3;                          // column
  int lane = threadIdx.x & 63;
  int grp  = lane & 60;

  const float* th = theta + (size_t)pair * 15;

  const float pr_[4][4] = {{1,0,0,1},{0,1,1,0},{0,0,0,0},{1,0,0,-1}};
  const float pi_[4][4] = {{0,0,0,0},{0,0,0,0},{0,-1,1,0},{0,0,0,0}};

  float Hre[16], Him[16];
#pragma unroll
  for (int e = 0; e < 16; ++e) { Hre[e] = 0.f; Him[e] = 0.f; }
  float tsum = 0.f;
#pragma unroll
  for (int m = 0; m < 15; ++m) {
    float tv = th[m];
    tsum += fabsf(tv);
    const int code = m + 1;
    const int a = code >> 2, c = code & 3;
#pragma unroll
    for (int i = 0; i < 4; ++i)
#pragma unroll
      for (int jj = 0; jj < 4; ++jj) {
        float ar = pr_[a][(i >> 1) * 2 + (jj >> 1)], ai = pi_[a][(i >> 1) * 2 + (jj >> 1)];
        float br = pr_[c][(i & 1) * 2 + (jj & 1)],   bi = pi_[c][(i & 1) * 2 + (jj & 1)];
        Hre[i * 4 + jj] += tv * (ar * br - ai * bi);
        Him[i * 4 + jj] += tv * (ar * bi + ai * br);
      }
  }
  int s = 0;
  if (tsum > 0.25f) {
    s = (int)ceilf(log2f(tsum * 4.0f));
    if (s < 0) s = 0;
    if (s > 14) s = 14;
  }
  float sc = exp2f((float)(-s));
  float Gre[16], Gim[16];
#pragma unroll
  for (int e = 0; e < 16; ++e) { Gre[e] = -Him[e] * sc; Gim[e] = Hre[e] * sc; }

  float Tcr[4], Tci[4];
#pragma unroll
  for (int i = 0; i < 4; ++i) {
    Tcr[i] = Gre[i * 4 + j] * (1.f / 9.f) + ((i == j) ? 1.f : 0.f);
    Tci[i] = Gim[i * 4 + j] * (1.f / 9.f);
  }
#pragma unroll
  for (int k = 8; k >= 1; --k) {
    float nr[4], ni[4];
    float invk = 1.0f / (float)k;
#pragma unroll
    for (int i = 0; i < 4; ++i) {
      float xr = 0.f, xi = 0.f;
#pragma unroll
      for (int l = 0; l < 4; ++l) {
        xr = fmaf(Gre[i * 4 + l], Tcr[l], fmaf(-Gim[i * 4 + l], Tci[l], xr));
        xi = fmaf(Gre[i * 4 + l], Tci[l], fmaf( Gim[i * 4 + l], Tcr[l], xi));
      }
      nr[i] = invk * xr + ((i == j) ? 1.f : 0.f);
      ni[i] = invk * xi;
    }
#pragma unroll
    for (int i = 0; i < 4; ++i) { Tcr[i] = nr[i]; Tci[i] = ni[i]; }
  }
  for (int it = 0; it < s; ++it) {
    float nr[4] = {0.f, 0.f, 0.f, 0.f}, ni[4] = {0.f, 0.f, 0.f, 0.f};
#pragma unroll
    for (int l = 0; l < 4; ++l) {
      int src = grp | l;
      float tlr = Tcr[l], tli = Tci[l];
#pragma unroll
      for (int i = 0; i < 4; ++i) {
        float br = __shfl(Tcr[i], src);
        float bi = __shfl(Tci[i], src);
        nr[i] = fmaf(br, tlr, fmaf(-bi, tli, nr[i]));
        ni[i] = fmaf(br, tli, fmaf( bi, tlr, ni[i]));
      }
    }
#pragma unroll
    for (int i = 0; i < 4; ++i) { Tcr[i] = nr[i]; Tci[i] = ni[i]; }
  }
#pragma unroll
  for (int i = 0; i < 4; ++i)
    Ubuf[(size_t)pair * 16 + i * 4 + j] = make_float2(Tcr[i], Tci[i]);
}

// ---------------------------------------------------------------------------
// qsim helpers
// ---------------------------------------------------------------------------
template<int S>
__device__ __forceinline__ int grpbase(int t) {
  return ((t >> S) << (S + 4)) | (t & ((1 << S) - 1));
}
template<int S>
__device__ __forceinline__ void ldgrp(const float2* st, int base, float* vr, float* vi) {
#pragma unroll
  for (int k = 0; k < 16; ++k) {
    float2 v = st[F2(base + (k << S))];
    vr[k] = v.x; vi[k] = v.y;
  }
}
template<int S>
__device__ __forceinline__ void stgrp(float2* st, int base, const float* vr, const float* vi) {
#pragma unroll
  for (int k = 0; k < 16; ++k) st[F2(base + (k << S))] = make_float2(vr[k], vi[k]);
}
__device__ __forceinline__ int base2s(int t) {
  return ((t >> 7) << 11) | (((t >> 5) & 3) << 7) | (t & 31);
}
__device__ __forceinline__ int addr2s(int base, int k) {
  return base + ((k >> 2) << 9) + ((k & 3) << 5);
}
__device__ __forceinline__ void ldgrp2(const float2* st, int base, float* vr, float* vi) {
#pragma unroll
  for (int k = 0; k < 16; ++k) {
    float2 v = st[F2(addr2s(base, k))];
    vr[k] = v.x; vi[k] = v.y;
  }
}
__device__ __forceinline__ void stgrp2(float2* st, int base, const float* vr, const float* vi) {
#pragma unroll
  for (int k = 0; k < 16; ++k) st[F2(addr2s(base, k))] = make_float2(vr[k], vi[k]);
}

__device__ __forceinline__ void loadU(const float2* __restrict__ Ug, float* ur, float* ui) {
#pragma unroll
  for (int e = 0; e < 16; ++e) {
    float2 u = Ug[e];
    ur[e] = sbc(u.x); ui[e] = sbc(u.y);
  }
}

__device__ __forceinline__ void applyU_hi(float* vr, float* vi, const float* ur, const float* ui) {
#pragma unroll
  for (int j2 = 0; j2 < 4; ++j2) {
    float ar[4], ai[4];
#pragma unroll
    for (int j = 0; j < 4; ++j) { ar[j] = vr[4 * j + j2]; ai[j] = vi[4 * j + j2]; }
#pragma unroll
    for (int i = 0; i < 4; ++i) {
      float xr = 0.f, xi = 0.f;
#pragma unroll
      for (int j = 0; j < 4; ++j) {
        xr = fmaf(ur[4 * i + j], ar[j], fmaf(-ui[4 * i + j], ai[j], xr));
        xi = fmaf(ur[4 * i + j], ai[j], fmaf( ui[4 * i + j], ar[j], xi));
      }
      vr[4 * i + j2] = xr; vi[4 * i + j2] = xi;
    }
  }
}
__device__ __forceinline__ void applyU_lo(float* vr, float* vi, const float* ur, const float* ui) {
#pragma unroll
  for (int i2 = 0; i2 < 4; ++i2) {
    float ar[4], ai[4];
#pragma unroll
    for (int j = 0; j < 4; ++j) { ar[j] = vr[4 * i2 + j]; ai[j] = vi[4 * i2 + j]; }
#pragma unroll
    for (int i = 0; i < 4; ++i) {
      float xr = 0.f, xi = 0.f;
#pragma unroll
      for (int j = 0; j < 4; ++j) {
        xr = fmaf(ur[4 * i + j], ar[j], fmaf(-ui[4 * i + j], ai[j], xr));
        xi = fmaf(ur[4 * i + j], ai[j], fmaf( ui[4 * i + j], ar[j], xi));
      }
      vr[4 * i2 + i] = xr; vi[4 * i2 + i] = xi;
    }
  }
}
__device__ __forceinline__ void applyU_mid(float* vr, float* vi, const float* ur, const float* ui) {
#pragma unroll
  for (int o = 0; o < 4; ++o) {
    const int kb = ((o >> 1) << 3) | (o & 1);
    float ar[4], ai[4];
#pragma unroll
    for (int j = 0; j < 4; ++j) { ar[j] = vr[kb | (j << 1)]; ai[j] = vi[kb | (j << 1)]; }
#pragma unroll
    for (int i = 0; i < 4; ++i) {
      float xr = 0.f, xi = 0.f;
#pragma unroll
      for (int j = 0; j < 4; ++j) {
        xr = fmaf(ur[4 * i + j], ar[j], fmaf(-ui[4 * i + j], ai[j], xr));
        xi = fmaf(ur[4 * i + j], ai[j], fmaf( ui[4 * i + j], ar[j], xi));
      }
      vr[kb | (i << 1)] = xr; vi[kb | (i << 1)] = xi;
    }
  }
}

template<int B>
__device__ __forceinline__ void ry16(float* vr, float* vi, float c, float s) {
#pragma unroll
  for (int k = 0; k < 16; ++k) {
    if (!(k & (1 << B))) {
      const int k1 = k | (1 << B);
      float r0 = vr[k], i0 = vi[k], r1 = vr[k1], i1 = vi[k1];
      vr[k]  = fmaf(c, r0, -s * r1);  vi[k]  = fmaf(c, i0, -s * i1);
      vr[k1] = fmaf(s, r0,  c * r1);  vi[k1] = fmaf(s, i0,  c * i1);
    }
  }
}
template<int CB, int TB>
__device__ __forceinline__ void cx16(float* vr, float* vi) {
#pragma unroll
  for (int k = 0; k < 16; ++k) {
    if ((k & (1 << CB)) && !(k & (1 << TB))) {
      const int k1 = k | (1 << TB);
      float tr = vr[k]; vr[k] = vr[k1]; vr[k1] = tr;
      float ti = vi[k]; vi[k] = vi[k1]; vi[k1] = ti;
    }
  }
}

template<int S>
__device__ __forceinline__ void enc_pass3(float2* st, const float2* __restrict__ U,
                                          int gHi, int gLo, int gMid, int b, int t) {
  float ur[16], ui[16], vr[16], vi[16];
  int base = grpbase<S>(t);
  ldgrp<S>(st, base, vr, vi);
  loadU(U + ((size_t)gHi  * BATCH + b) * 16, ur, ui); applyU_hi (vr, vi, ur, ui);
  loadU(U + ((size_t)gLo  * BATCH + b) * 16, ur, ui); applyU_lo (vr, vi, ur, ui);
  loadU(U + ((size_t)gMid * BATCH + b) * 16, ur, ui); applyU_mid(vr, vi, ur, ui);
  stgrp<S>(st, base, vr, vi);
}
__device__ __forceinline__ void enc_passD(float2* st, const float2* __restrict__ U,
                                          int gLo, int gMid, int b, int t) {
  float ur[16], ui[16], vr[16], vi[16];
  int base = t << 4;
  ldgrp<0>(st, base, vr, vi);
  loadU(U + ((size_t)gLo  * BATCH + b) * 16, ur, ui); applyU_lo (vr, vi, ur, ui);
  loadU(U + ((size_t)gMid * BATCH + b) * 16, ur, ui); applyU_mid(vr, vi, ur, ui);
  stgrp<0>(st, base, vr, vi);
}
__device__ __forceinline__ void enc_passE(float2* st, const float2* __restrict__ U,
                                          int gA, int gB, int b, int t) {
  float ur[16], ui[16], vr[16], vi[16];
  int base = base2s(t);
  ldgrp2(st, base, vr, vi);
  loadU(U + ((size_t)gA * BATCH + b) * 16, ur, ui); applyU_hi(vr, vi, ur, ui);
  loadU(U + ((size_t)gB * BATCH + b) * 16, ur, ui); applyU_lo(vr, vi, ur, ui);
  stgrp2(st, base, vr, vi);
}
template<int S>
__device__ __forceinline__ void var_pass3(float2* st, const float* __restrict__ vp,
                                          int l, int qbase, int t) {
  float vr[16], vi[16];
  int base = grpbase<S>(t);
  ldgrp<S>(st, base, vr, vi);
  float c[4], sn[4];
#pragma unroll
  for (int i = 0; i < 4; ++i) {
    float a = sbc(vp[l * NQ + qbase + i]) * 0.5f;
    c[i] = cosf(a); sn[i] = sinf(a);
  }
  ry16<3>(vr, vi, c[0], sn[0]);
  ry16<2>(vr, vi, c[1], sn[1]);
  ry16<1>(vr, vi, c[2], sn[2]);
  ry16<0>(vr, vi, c[3], sn[3]);
  cx16<3, 2>(vr, vi);
  cx16<1, 0>(vr, vi);
  cx16<2, 1>(vr, vi);
  stgrp<S>(st, base, vr, vi);
}
__device__ __forceinline__ void var_passD(float2* st, const float* __restrict__ vp,
                                          int l, int t) {
  float vr[16], vi[16];
  int base = t << 4;
  ldgrp<0>(st, base, vr, vi);
  float a0 = sbc(vp[l * NQ + 12]) * 0.5f;
  float a1 = sbc(vp[l * NQ + 13]) * 0.5f;
  ry16<1>(vr, vi, cosf(a0), sinf(a0));
  ry16<0>(vr, vi, cosf(a1), sinf(a1));
  cx16<1, 0>(vr, vi);
  cx16<2, 1>(vr, vi);
  stgrp<0>(st, base, vr, vi);
}
__device__ __forceinline__ void var_passE(float2* st, int t) {
  float vr[16], vi[16];
  int base = base2s(t);
  ldgrp2(st, base, vr, vi);
  cx16<3, 2>(vr, vi);
  cx16<1, 0>(vr, vi);
  stgrp2(st, base, vr, vi);
}

// ---------------------------------------------------------------------------
// Kernel 3: statevector sim. TWO blocks per batch element (redundant gate
// evolution on otherwise-idle CUs); obs split by w-parity; observable
// coefficients via block-uniform global reads (scalar s_load path).
// ---------------------------------------------------------------------------
__global__ __launch_bounds__(1024) void qsim_kernel(
    const float2* __restrict__ U, const float* __restrict__ var_params,
    const float* __restrict__ A, const float* __restrict__ Bp,
    const float* __restrict__ D, const float* __restrict__ Wh,
    const float* __restrict__ bh, float* __restrict__ out)
{
  __shared__ float2 st[PHYS2];
  __shared__ float red[6][16];       // per-(obs, wave) partials

  const int t = threadIdx.x;
  const int b = blockIdx.x >> 1;
  const int h = blockIdx.x & 1;      // obs parity this block handles
  const int nw = h ? 5 : 6;

  for (int i = t; i < PHYS2; i += 1024)
    st[i] = (i == 0) ? make_float2(1.f, 0.f) : make_float2(0.f, 0.f);
  __syncthreads();

  // ---- encoding: 2 blocks x 5 fused passes (13 gates each) ----
  for (int nb = 0; nb < 2; ++nb) {
    int gI = nb * 13;
    enc_pass3<10>(st, U, gI + 0, gI + 1, gI + 7,  b, t); __syncthreads();
    enc_pass3<6 >(st, U, gI + 2, gI + 3, gI + 9,  b, t); __syncthreads();
    enc_pass3<2 >(st, U, gI + 4, gI + 5, gI + 11, b, t); __syncthreads();
    enc_passD    (st, U, gI + 6, gI + 12,         b, t); __syncthreads();
    enc_passE    (st, U, gI + 8, gI + 10,         b, t); __syncthreads();
  }

  // ---- variational: 3 layers x 5 fused passes ----
  for (int l = 0; l < DEPTH; ++l) {
    var_pass3<10>(st, var_params, l, 0, t); __syncthreads();
    var_pass3<6 >(st, var_params, l, 4, t); __syncthreads();
    var_pass3<2 >(st, var_params, l, 8, t); __syncthreads();
    var_passD    (st, var_params, l,    t); __syncthreads();
    var_passE    (st, t);                   __syncthreads();
  }

  // ---- expectation values: y-form, coefficients via uniform global reads
  const int wave = t >> 6;
  for (int idx = 0; idx < nw; ++idx) {
    const int w = 2 * idx + h;                 // block-uniform
    const float* __restrict__ Aw = A + w * NOFF;
    const float* __restrict__ Bw = Bp + w * NOFF;
    const float* __restrict__ Dw = D + w * KDIM;
    const int shift = 10 - w;
    const int hi2 = t >> shift;
    const int lo = t & ((1 << shift) - 1);
    const int base2 = (hi2 << (shift + 4)) | lo;
    float sr[16], si[16];
#pragma unroll
    for (int k = 0; k < 16; ++k) {
      float2 v = st[F2(base2 + (k << shift))];
      sr[k] = v.x; si[k] = v.y;
    }
    // y_k = d_k s_k + sum_{l<k} (A_p + i B_p) s_l
    float yr[16], yi[16];
#pragma unroll
    for (int k = 0; k < 16; ++k) {
      float dk = (k < 15) ? Dw[k + 1] : 0.f;
      yr[k] = dk * sr[k];
      yi[k] = dk * si[k];
    }
#pragma unroll
    for (int k = 1; k < 16; ++k) {
#pragma unroll
      for (int l2 = 0; l2 < k; ++l2) {
        const int pidx = (k * (k - 1)) / 2 + l2;
        const float a = Aw[pidx];
        const float q = Bw[pidx];
        yr[k] = fmaf(a, sr[l2], fmaf(-q, si[l2], yr[k]));
        yi[k] = fmaf(a, si[l2], fmaf( q, sr[l2], yi[k]));
      }
    }
    float E = 0.f;
#pragma unroll
    for (int k = 0; k < 16; ++k)
      E = fmaf(sr[k], yr[k], fmaf(si[k], yi[k], E));
    E *= 2.0f;
#pragma unroll
    for (int off = 32; off; off >>= 1) E += __shfl_xor(E, off);
    if ((t & 63) == 0) red[idx][wave] = E;
  }
  __syncthreads();

  // ---- head: partial contribution, accumulated atomically ----
  if (t < OUTDIM) {
    float o = (h == 0) ? bh[t] : 0.f;
    for (int idx = 0; idx < nw; ++idx) {
      const int w = 2 * idx + h;
      float q = 0.f;
#pragma unroll
      for (int ww = 0; ww < 16; ++ww) q += red[idx][ww];
      o = fmaf(Wh[t * NOBS + w], q, o);
    }
    atomicAdd(&out[b * OUTDIM + t], o);
  }
}

extern "C" void kernel_launch(void* const* d_in, const int* in_sizes, int n_in,
                              void* d_out, int out_size, void* d_ws, size_t ws_size,
                              hipStream_t stream) {
  const float* x          = (const float*)d_in[0];
  const float* W_enc      = (const float*)d_in[1];
  const float* b_enc      = (const float*)d_in[2];
  const float* var_params = (const float*)d_in[3];
  const float* A          = (const float*)d_in[4];
  const float* Bp         = (const float*)d_in[5];
  const float* D          = (const float*)d_in[6];
  const float* W_head     = (const float*)d_in[7];
  const float* b_head     = (const float*)d_in[8];
  float* out = (float*)d_out;

  float*  theta = (float*)d_ws;                                    // 3328*15 f32
  size_t  thBytes = (size_t)3328 * 15 * sizeof(float);
  float2* Ubuf = (float2*)((char*)d_ws + ((thBytes + 255) / 256) * 256);

  hipMemsetAsync(out, 0, (size_t)out_size * sizeof(float), stream);
  enc_kernel <<<832, 256, 0, stream>>>(x, W_enc, b_enc, theta);
  expm_kernel<<<52,  256, 0, stream>>>(theta, Ubuf);
  qsim_kernel<<<256, 1024, 0, stream>>>(Ubuf, var_params, A, Bp, D,
                                        W_head, b_head, out);
}